// Round 3
// baseline (264.788 us; speedup 1.0000x reference)
//
#include <hip/hip_runtime.h>

// ---------------------------------------------------------------------------
// LSTM (Alex Graves) single step, batch 8192 — fused GEMM+epilogue, r8.
// Faithful m201 8-phase port (r7 was the m196 anti-pattern: lumped prefetch
// + coarse phases = documented -7..-27%). Changes vs r7:
//   * ks-major phases: ph = ks*2+mh, so K-half LDS regions free EARLY
//     (ks0 of tile X free after phase (X,1)) -> fine-grained stage rotation.
//   * LDS unit = (matrix, K-half) = 16 KB; ONE unit (2 global_load_lds)
//     staged per phase — m201's exact 2-loads/phase rhythm.
//   * counted s_waitcnt vmcnt(8) at ends of phases 1,3 only (never 0
//     mid-loop; ledger-traced incl. tail t=10: vmcnt(4), t=11: vmcnt(0)).
//   * double-barrier phases + setprio(1) around each 16-MFMA cluster.
// LDS granule (per 32KB matrix-tile): L = ks*1024 + row*4 + (c2^xr(row)),
// xr(row)=(row&3)^((row>>2)&3): 2-way banks on ds_read_b128, 64B-segment
// coalesced global side, linear gload_lds dest (both-sides swizzle, rule 21).
//   A = [H | x[:,n,:]] (8192x768) fp16;  W rows permuted: gate g=(c>>4)&3,
//   jj=((c>>6)<<4)|(c&15). out[0:8192*512)=cm ; out[8192*512:)=h
// ---------------------------------------------------------------------------

typedef _Float16 half8 __attribute__((ext_vector_type(8)));
typedef _Float16 half4v __attribute__((ext_vector_type(4)));
typedef float floatx4 __attribute__((ext_vector_type(4)));

#define BATCH 8192
#define NSTEPS 16
#define IN_F 256
#define OUT_F 512
#define KDIM 768    // OUT_F + IN_F
#define NDIM 2048   // 4 * OUT_F
#define HSIZE ((size_t)BATCH * OUT_F)

#define BM 256
#define BN 256
#define BK 64
#define NKT (KDIM / BK)   // 12

__device__ __forceinline__ void async_copy16(const void* gptr, void* lptr) {
  __builtin_amdgcn_global_load_lds(
      (const __attribute__((address_space(1))) unsigned int*)gptr,
      (__attribute__((address_space(3))) unsigned int*)lptr,
      16, 0, 0);
}

__device__ __forceinline__ float sigmoidf_(float x) {
  return 1.0f / (1.0f + __expf(-x));
}

__device__ __forceinline__ float tanhf_(float x) {
  x = fminf(fmaxf(x, -20.0f), 20.0f);   // __expf(|2x|>~176) would inf->NaN
  float e = __expf(2.0f * x);
  return (e - 1.0f) / (e + 1.0f);
}

// ------------------- merged pack: A rows then W rows -----------------------
#define PACK_ROWS 8
__global__ void pack_AW(const float* __restrict__ H, const float* __restrict__ x,
                        const int* __restrict__ nptr,
                        const float* __restrict__ fg_w_h, const float* __restrict__ fg_w_x,
                        const float* __restrict__ ig_w_h, const float* __restrict__ ig_w_x,
                        const float* __restrict__ in_w_h, const float* __restrict__ in_w_x,
                        const float* __restrict__ og_w_h, const float* __restrict__ og_w_x,
                        _Float16* __restrict__ A, _Float16* __restrict__ W) {
  const int k = threadIdx.x * 4;
  const int n = *nptr;
  const int row0 = blockIdx.x * PACK_ROWS;
#pragma unroll
  for (int rr = 0; rr < PACK_ROWS; ++rr) {
    const int blk = row0 + rr;
    const float* src;
    _Float16* dst;
    if (blk < BATCH) {
      const int b = blk;
      if (k < OUT_F) {
        src = H + (size_t)b * OUT_F + k;
      } else {
        src = x + ((size_t)b * NSTEPS + n) * IN_F + (k - OUT_F);
      }
      dst = A + (size_t)b * KDIM + k;
    } else {
      const int row = blk - BATCH;
      const int g  = (row >> 4) & 3;
      const int jj = ((row >> 6) << 4) | (row & 15);
      if (k < OUT_F) {
        const float* wh = (g == 0) ? fg_w_h : (g == 1) ? ig_w_h : (g == 2) ? in_w_h : og_w_h;
        src = wh + (size_t)jj * OUT_F + k;
      } else {
        const float* wx = (g == 0) ? fg_w_x : (g == 1) ? ig_w_x : (g == 2) ? in_w_x : og_w_x;
        src = wx + (size_t)jj * IN_F + (k - OUT_F);
      }
      dst = W + (size_t)row * KDIM + k;
    }
    float4 v = *(const float4*)src;
    half4v h = {(_Float16)v.x, (_Float16)v.y, (_Float16)v.z, (_Float16)v.w};
    *(half4v*)dst = h;
  }
}

// ---------------------- fused GEMM + gate epilogue -------------------------
// 256x256 tile, BK=64, 512 thr / 8 waves (2M x 4N), wave = 128x64 output.
// LDS: 2 slots x (A 32KB + B 32KB) = 128 KB.
// Phase (X, ph) with ks=ph>>1, mh=ph&1:
//   reads:  af[4] (M-frags mh*4..+4, K-half ks), bf[4] (K-half ks)
//   stage:  ph0: A-ks1(X+1)  ph1: B-ks1(X+1)  ph2: A-ks0(X+2)  ph3: B-ks0(X+2)
//           (each 16 KB unit lands in a region whose last reader finished
//            before the preceding post-barrier — ledger in comments)
//   barrier; setprio(1); 16 MFMA; setprio(0);
//   [end ph1: vmcnt(8) — publishes ks1(X);  end ph3: vmcnt(8) — ks0(X+1)]
//   barrier.
__global__ __launch_bounds__(512, 2) void gemm_lstm(
    const _Float16* __restrict__ A, const _Float16* __restrict__ W,
    const float* __restrict__ C,
    const float* __restrict__ fg_w_c, const float* __restrict__ fg_b,
    const float* __restrict__ ig_w_c, const float* __restrict__ ig_b,
    const float* __restrict__ in_b,
    const float* __restrict__ og_w_cn, const float* __restrict__ og_b,
    float* __restrict__ out) {
  __shared__ __align__(16) char smem[131072];

  const int tid = threadIdx.x;
  const int lane = tid & 63;
  const int wave = tid >> 6;       // 0..7
  const int quad = lane >> 4;
  const int l16 = lane & 15;
  const int wm = wave >> 2;        // 0..1  (M half: 128 rows)
  const int wn = wave & 3;         // 0..3  (N quarter: 64 cols)

  // T1 bijective XCD swizzle (256 blocks % 8 == 0)
  const int bid = blockIdx.x;
  const int swz = (bid & 7) * 32 + (bid >> 3);
  const int bx = swz & 7;          // N-tile 0..7
  const int by = swz >> 3;         // M-tile 0..31
  const int m0 = by * BM;
  const int n0 = bx * BN;

  const int jj = (((n0 + wn * 64) >> 6) << 4) | l16;
  const float fwc = fg_w_c[jj], fb = fg_b[jj];
  const float iwc = ig_w_c[jj], ib = ig_b[jj];
  const float nb  = in_b[jj];
  const float owc = og_w_cn[jj], ob = og_b[jj];

  floatx4 acc[8][4] = {};

  // stage one 16 KB unit: (tile X, mat 0=A/1=B, K-half ks) -> slot X&1.
  // LDS granule (linear dest): ks*1024 + g*512 + tid ; holds global
  // (row = L>>2, chunk = ks*4 + ((L&3) ^ xr(row))).
  auto stageU = [&](int X, int mat, int ks) {
    const _Float16* src = mat ? W : A;
    const int gb = mat ? n0 : m0;
    char* base = smem + (X & 1) * 65536 + mat * 32768 + ks * 16384;
    const int kt = X * BK + ks * 32;
#pragma unroll
    for (int g = 0; g < 2; ++g) {
      const int Ll = g * 512 + tid;
      const int row = Ll >> 2;
      const int c2 = (Ll & 3) ^ ((row & 3) ^ ((row >> 2) & 3));
      async_copy16(src + (size_t)(gb + row) * KDIM + kt + c2 * 8,
                   base + Ll * 16);
    }
  };

  // prologue: 6 units (deadline order), keep newest 8 loads in flight
  stageU(0, 0, 0); stageU(0, 1, 0); stageU(0, 0, 1);
  stageU(0, 1, 1); stageU(1, 0, 0); stageU(1, 1, 0);
  asm volatile("s_waitcnt vmcnt(8)" ::: "memory");  // ks0(0) arrived
  asm volatile("s_barrier" ::: "memory");           // ks0(0) published

#pragma unroll 2
  for (int t = 0; t < NKT; ++t) {
    const _Float16* As = (const _Float16*)(smem + (t & 1) * 65536);
    const _Float16* Bs = (const _Float16*)(smem + (t & 1) * 65536 + 32768);
#pragma unroll
    for (int ph = 0; ph < 4; ++ph) {
      const int ks = ph >> 1, mh = ph & 1;
      // ---- ds_read fragments (granule: ks*1024 + row*4 + (quad^xr(row)))
      half8 af[4], bf[4];
#pragma unroll
      for (int j = 0; j < 4; ++j) {
        const int row = wn * 64 + j * 16 + l16;
        const int L = ks * 1024 + row * 4 + (quad ^ ((row & 3) ^ ((row >> 2) & 3)));
        bf[j] = *(const half8*)(Bs + L * 8);
      }
#pragma unroll
      for (int i = 0; i < 4; ++i) {
        const int row = wm * 128 + (mh * 4 + i) * 16 + l16;
        const int L = ks * 1024 + row * 4 + (quad ^ ((row & 3) ^ ((row >> 2) & 3)));
        af[i] = *(const half8*)(As + L * 8);
      }
      // ---- stage-issue (one unit; target region freed at an earlier barrier)
      if (ph == 0)      { if (t + 1 < NKT) stageU(t + 1, 0, 1); }  // ks1(t-1) freed @(t-1,3)
      else if (ph == 1) { if (t + 1 < NKT) stageU(t + 1, 1, 1); }
      else if (ph == 2) { if (t + 2 < NKT) stageU(t + 2, 0, 0); }  // ks0(t) freed @(t,1)
      else              { if (t + 2 < NKT) stageU(t + 2, 1, 0); }
      asm volatile("s_barrier" ::: "memory");
      __builtin_amdgcn_s_setprio(1);
#pragma unroll
      for (int i = 0; i < 4; ++i)
#pragma unroll
        for (int j = 0; j < 4; ++j)
          acc[mh * 4 + i][j] = __builtin_amdgcn_mfma_f32_16x16x32_f16(
              af[i], bf[j], acc[mh * 4 + i][j], 0, 0, 0);
      __builtin_amdgcn_s_setprio(0);
      // ---- counted arrival waits (publication = following barrier)
      if (ph == 1) {                       // next phase reads ks1(t)
        if (t < NKT - 1) asm volatile("s_waitcnt vmcnt(8)" ::: "memory");
        else             asm volatile("s_waitcnt vmcnt(0)" ::: "memory");
      } else if (ph == 3 && t + 1 < NKT) { // next tile reads ks0(t+1)
        if (t + 1 == NKT - 1) asm volatile("s_waitcnt vmcnt(4)" ::: "memory");
        else                  asm volatile("s_waitcnt vmcnt(8)" ::: "memory");
      }
      asm volatile("s_barrier" ::: "memory");
    }
  }

  // ---- epilogue. C/D: col=lane&15 (=jj lane), row=quad*4+r ----
  // Final post-barrier fenced all LDS reads; vmcnt queue empty.
  float* cmS = (float*)smem;              // 256 x 64
  float* hS  = (float*)(smem + 65536);    // 256 x 64

  const int jjloc = wn * 16 + l16;        // 0..63 within block tile
#pragma unroll
  for (int i = 0; i < 8; ++i) {
    const int rbase = m0 + wm * 128 + i * 16 + quad * 4;
    float cv[4];
#pragma unroll
    for (int r = 0; r < 4; ++r)
      cv[r] = C[(size_t)(rbase + r) * OUT_F + jj];
#pragma unroll
    for (int r = 0; r < 4; ++r) {
      const float c = cv[r];
      const float inn = tanhf_(acc[i][2][r] + nb);
      const float fg  = sigmoidf_(fwc * c + acc[i][0][r] + fb);
      const float ig  = sigmoidf_(iwc * c + acc[i][1][r] + ib);
      const float cm  = fg * c + ig * inn;
      const float og  = sigmoidf_(owc * cm + acc[i][3][r] + ob);
      const int rloc = wm * 128 + i * 16 + quad * 4 + r;
      cmS[rloc * 64 + jjloc] = cm;
      hS [rloc * 64 + jjloc] = og * tanhf_(cm);
    }
  }
  __syncthreads();

  // cooperative coalesced store: 256 rows x 64 cols; 256B contiguous per row.
  const int ub = bx * 64;
#pragma unroll
  for (int q = 0; q < 8; ++q) {
    const int idx = q * 512 + tid;
    const int row = idx >> 4;            // 0..255
    const int c4 = idx & 15;             // float4 slot within row
    const size_t gbase = (size_t)(m0 + row) * OUT_F + ub + c4 * 4;
    *(float4*)(out + gbase) = *(const float4*)(cmS + row * 64 + c4 * 4);
    *(float4*)(out + HSIZE + gbase) = *(const float4*)(hS + row * 64 + c4 * 4);
  }
}

// ---------------------------------------------------------------------------
extern "C" void kernel_launch(void* const* d_in, const int* in_sizes, int n_in,
                              void* d_out, int out_size, void* d_ws, size_t ws_size,
                              hipStream_t stream) {
  const float* x       = (const float*)d_in[0];
  const float* C       = (const float*)d_in[1];
  const float* H       = (const float*)d_in[2];
  const float* fg_w_c  = (const float*)d_in[3];
  const float* fg_w_h  = (const float*)d_in[4];
  const float* fg_w_x  = (const float*)d_in[5];
  const float* fg_b    = (const float*)d_in[6];
  const float* ig_w_c  = (const float*)d_in[7];
  const float* ig_w_h  = (const float*)d_in[8];
  const float* ig_w_x  = (const float*)d_in[9];
  const float* ig_b    = (const float*)d_in[10];
  const float* in_w_h  = (const float*)d_in[11];
  const float* in_w_x  = (const float*)d_in[12];
  const float* in_b    = (const float*)d_in[13];
  const float* og_w_cn = (const float*)d_in[14];
  const float* og_w_h  = (const float*)d_in[15];
  const float* og_w_x  = (const float*)d_in[16];
  const float* og_b    = (const float*)d_in[17];
  const int*   nptr    = (const int*)d_in[18];

  char* ws = (char*)d_ws;
  _Float16* Apk = (_Float16*)ws;                // 8192*768*2 = 12,582,912 B
  _Float16* Wpk = (_Float16*)(ws + 12582912);   // 2048*768*2 =  3,145,728 B
  (void)ws_size; (void)in_sizes; (void)n_in; (void)out_size;

  pack_AW<<<(BATCH + NDIM) / PACK_ROWS, 192, 0, stream>>>(
      H, x, nptr,
      fg_w_h, fg_w_x, ig_w_h, ig_w_x,
      in_w_h, in_w_x, og_w_h, og_w_x,
      Apk, Wpk);
  gemm_lstm<<<dim3(256), 512, 0, stream>>>(Apk, Wpk, C,
                                           fg_w_c, fg_b, ig_w_c, ig_b, in_b,
                                           og_w_cn, og_b, (float*)d_out);
}

// Round 4
// 261.597 us; speedup vs baseline: 1.0122x; 1.0122x over previous
//
#include <hip/hip_runtime.h>

// ---------------------------------------------------------------------------
// LSTM (Alex Graves) single step, batch 8192 — fused GEMM+epilogue, r9.
// gemm_lstm: byte-identical revert to r5 (best measured 254.0/254.3 us) —
//   128x128 tile, 4 blocks/CU, m97-style loop. r6/r7/r8 structure probes
//   (2-phase dbuf, coarse counted-vmcnt, faithful 8-phase) all regressed
//   (+5..+10 us): at K=768 (12 K-steps) deep pipelines never reach steady
//   state and 1-block/CU kills cross-block epilogue/K-loop overlap (m114).
// pack_AW: isolated change — 16 rows/block (640 blocks vs r5's 10240).
//   r5 pack was 24B-of-work-per-thread launch-machinery-bound; r6's pack fix
//   was confounded with a gemm regression. Block boundary at row 8192 is
//   16-aligned -> every block is pure-A or pure-W (uniform branches).
// ---------------------------------------------------------------------------

typedef _Float16 half8 __attribute__((ext_vector_type(8)));
typedef _Float16 half4v __attribute__((ext_vector_type(4)));
typedef float floatx4 __attribute__((ext_vector_type(4)));

#define BATCH 8192
#define NSTEPS 16
#define IN_F 256
#define OUT_F 512
#define KDIM 768    // OUT_F + IN_F
#define NDIM 2048   // 4 * OUT_F
#define HSIZE ((size_t)BATCH * OUT_F)

#define BM 128
#define BN 128
#define BK 64

__device__ __forceinline__ void async_copy16(const void* gptr, void* lptr) {
  __builtin_amdgcn_global_load_lds(
      (const __attribute__((address_space(1))) unsigned int*)gptr,
      (__attribute__((address_space(3))) unsigned int*)lptr,
      16, 0, 0);
}

__device__ __forceinline__ float sigmoidf_(float x) {
  return 1.0f / (1.0f + __expf(-x));
}

__device__ __forceinline__ float tanhf_(float x) {
  x = fminf(fmaxf(x, -20.0f), 20.0f);   // __expf(|2x|>~176) would inf->NaN
  float e = __expf(2.0f * x);
  return (e - 1.0f) / (e + 1.0f);
}

// ------------------- merged pack: A rows then W rows -----------------------
// 16 rows/block: 640 blocks x 192 thr. Each thread: 16 independent
// float4-load -> half4-store pairs (good ILP, no cross-iteration deps).
#define PACK_ROWS 16
__global__ void pack_AW(const float* __restrict__ H, const float* __restrict__ x,
                        const int* __restrict__ nptr,
                        const float* __restrict__ fg_w_h, const float* __restrict__ fg_w_x,
                        const float* __restrict__ ig_w_h, const float* __restrict__ ig_w_x,
                        const float* __restrict__ in_w_h, const float* __restrict__ in_w_x,
                        const float* __restrict__ og_w_h, const float* __restrict__ og_w_x,
                        _Float16* __restrict__ A, _Float16* __restrict__ W) {
  const int k = threadIdx.x * 4;
  const int n = *nptr;
  const int row0 = blockIdx.x * PACK_ROWS;
#pragma unroll
  for (int rr = 0; rr < PACK_ROWS; ++rr) {
    const int blk = row0 + rr;
    const float* src;
    _Float16* dst;
    if (blk < BATCH) {
      const int b = blk;
      if (k < OUT_F) {
        src = H + (size_t)b * OUT_F + k;
      } else {
        src = x + ((size_t)b * NSTEPS + n) * IN_F + (k - OUT_F);
      }
      dst = A + (size_t)b * KDIM + k;
    } else {
      const int row = blk - BATCH;
      const int g  = (row >> 4) & 3;
      const int jj = ((row >> 6) << 4) | (row & 15);
      if (k < OUT_F) {
        const float* wh = (g == 0) ? fg_w_h : (g == 1) ? ig_w_h : (g == 2) ? in_w_h : og_w_h;
        src = wh + (size_t)jj * OUT_F + k;
      } else {
        const float* wx = (g == 0) ? fg_w_x : (g == 1) ? ig_w_x : (g == 2) ? in_w_x : og_w_x;
        src = wx + (size_t)jj * IN_F + (k - OUT_F);
      }
      dst = W + (size_t)row * KDIM + k;
    }
    float4 v = *(const float4*)src;
    half4v h = {(_Float16)v.x, (_Float16)v.y, (_Float16)v.z, (_Float16)v.w};
    *(half4v*)dst = h;
  }
}

// ---------------------- fused GEMM + gate epilogue -------------------------
// 128x128 tile, BK=64, 256 thr / 4 waves, each wave 64x64 (4x4 MFMA tiles).
// LDS 16B-granule XOR swizzle applied on the GLOBAL address side.
// Block's output region: rows m0..m0+127, units jj in [bx*32, bx*32+32):
// 128 B per row per tile -> full-line coalesced stores after LDS transpose.
__global__ __launch_bounds__(256, 4) void gemm_lstm(
    const _Float16* __restrict__ A, const _Float16* __restrict__ W,
    const float* __restrict__ C,
    const float* __restrict__ fg_w_c, const float* __restrict__ fg_b,
    const float* __restrict__ ig_w_c, const float* __restrict__ ig_b,
    const float* __restrict__ in_b,
    const float* __restrict__ og_w_cn, const float* __restrict__ og_b,
    float* __restrict__ out) {
  __shared__ __align__(16) char smem[32768];
  _Float16* As = (_Float16*)smem;            // 16 KB (K-loop)
  _Float16* Bs = (_Float16*)(smem + 16384);  // 16 KB (K-loop)
  float* cmS = (float*)smem;                 // 16 KB (epilogue, 128x32)
  float* hS  = (float*)(smem + 16384);       // 16 KB (epilogue, 128x32)

  const int tid = threadIdx.x;
  const int lane = tid & 63;
  const int wave = tid >> 6;
  const int quad = lane >> 4;
  const int l16 = lane & 15;
  const int m0 = blockIdx.y * BM;
  const int n0 = blockIdx.x * BN;
  const int mw = (wave >> 1) * 64;
  const int nw = (wave & 1) * 64;

  // this lane's output unit
  const int jj = (((n0 + nw) >> 6) << 4) | l16;
  const float fwc = fg_w_c[jj], fb = fg_b[jj];
  const float iwc = ig_w_c[jj], ib = ig_b[jj];
  const float nb  = in_b[jj];
  const float owc = og_w_cn[jj], ob = og_b[jj];

  floatx4 acc[4][4] = {};

  for (int kt = 0; kt < KDIM; kt += BK) {
    __syncthreads();
#pragma unroll
    for (int r = 0; r < 4; ++r) {
      const int g = r * 256 + tid;       // 16B granule index
      const int row = g >> 3;
      const int cl = g & 7;
      const int cg = cl ^ (row & 7);     // swizzled global chunk
      async_copy16(A + (size_t)(m0 + row) * KDIM + kt + cg * 8,
                   As + g * 8);
      async_copy16(W + (size_t)(n0 + row) * KDIM + kt + cg * 8,
                   Bs + g * 8);
    }
    __syncthreads();

#pragma unroll
    for (int ks = 0; ks < 2; ++ks) {
      half8 af[4], bf[4];
#pragma unroll
      for (int i = 0; i < 4; ++i) {
        const int row = mw + i * 16 + l16;
        const int chunk = ks * 4 + quad;
        const int gran = row * 8 + (chunk ^ (row & 7));
        af[i] = *(const half8*)(As + gran * 8);
      }
#pragma unroll
      for (int j = 0; j < 4; ++j) {
        const int row = nw + j * 16 + l16;
        const int chunk = ks * 4 + quad;
        const int gran = row * 8 + (chunk ^ (row & 7));
        bf[j] = *(const half8*)(Bs + gran * 8);
      }
#pragma unroll
      for (int i = 0; i < 4; ++i)
#pragma unroll
        for (int j = 0; j < 4; ++j)
          acc[i][j] = __builtin_amdgcn_mfma_f32_16x16x32_f16(af[i], bf[j], acc[i][j], 0, 0, 0);
    }
  }

  // ---- epilogue. C/D: col=lane&15 (=jj lane), row=quad*4+r ----
  // batched C loads first (overlap their HBM latency with tanh below)
  float cv[16];
#pragma unroll
  for (int i = 0; i < 4; ++i) {
    const int rbase = m0 + mw + i * 16 + quad * 4;
#pragma unroll
    for (int r = 0; r < 4; ++r)
      cv[i * 4 + r] = C[(size_t)(rbase + r) * OUT_F + jj];
  }
  float inn[16];
#pragma unroll
  for (int i = 0; i < 4; ++i)
#pragma unroll
    for (int r = 0; r < 4; ++r)
      inn[i * 4 + r] = tanhf_(acc[i][2][r] + nb);

  __syncthreads();   // all K-loop ds_reads complete before As/Bs overwrite

  const int jjloc = (nw >> 6) * 16 + l16;      // 0..31 within block tile
#pragma unroll
  for (int i = 0; i < 4; ++i) {
    const int rloc0 = mw + i * 16 + quad * 4;  // block-local row 0..127
#pragma unroll
    for (int r = 0; r < 4; ++r) {
      const float c = cv[i * 4 + r];
      const float fg  = sigmoidf_(fwc * c + acc[i][0][r] + fb);
      const float ig  = sigmoidf_(iwc * c + acc[i][1][r] + ib);
      const float cm  = fg * c + ig * inn[i * 4 + r];
      const float og  = sigmoidf_(owc * cm + acc[i][3][r] + ob);
      cmS[(rloc0 + r) * 32 + jjloc] = cm;
      hS [(rloc0 + r) * 32 + jjloc] = og * tanhf_(cm);
    }
  }
  __syncthreads();

  // cooperative coalesced store: 128 rows x 32 cols per tile; thread q-loop
  // covers 4 float4 each; wave = 8 rows x 128 B contiguous per instruction.
  const int bx32 = blockIdx.x * 32;
#pragma unroll
  for (int q = 0; q < 4; ++q) {
    const int idx = q * 256 + tid;
    const int row = idx >> 3;
    const int c4 = idx & 7;
    const size_t gbase = (size_t)(m0 + row) * OUT_F + bx32 + c4 * 4;
    *(float4*)(out + gbase) = *(const float4*)(cmS + row * 32 + c4 * 4);
    *(float4*)(out + HSIZE + gbase) = *(const float4*)(hS + row * 32 + c4 * 4);
  }
}

// ---------------------------------------------------------------------------
extern "C" void kernel_launch(void* const* d_in, const int* in_sizes, int n_in,
                              void* d_out, int out_size, void* d_ws, size_t ws_size,
                              hipStream_t stream) {
  const float* x       = (const float*)d_in[0];
  const float* C       = (const float*)d_in[1];
  const float* H       = (const float*)d_in[2];
  const float* fg_w_c  = (const float*)d_in[3];
  const float* fg_w_h  = (const float*)d_in[4];
  const float* fg_w_x  = (const float*)d_in[5];
  const float* fg_b    = (const float*)d_in[6];
  const float* ig_w_c  = (const float*)d_in[7];
  const float* ig_w_h  = (const float*)d_in[8];
  const float* ig_w_x  = (const float*)d_in[9];
  const float* ig_b    = (const float*)d_in[10];
  const float* in_w_h  = (const float*)d_in[11];
  const float* in_w_x  = (const float*)d_in[12];
  const float* in_b    = (const float*)d_in[13];
  const float* og_w_cn = (const float*)d_in[14];
  const float* og_w_h  = (const float*)d_in[15];
  const float* og_w_x  = (const float*)d_in[16];
  const float* og_b    = (const float*)d_in[17];
  const int*   nptr    = (const int*)d_in[18];

  char* ws = (char*)d_ws;
  _Float16* Apk = (_Float16*)ws;                // 8192*768*2 = 12,582,912 B
  _Float16* Wpk = (_Float16*)(ws + 12582912);   // 2048*768*2 =  3,145,728 B
  (void)ws_size; (void)in_sizes; (void)n_in; (void)out_size;

  pack_AW<<<(BATCH + NDIM) / PACK_ROWS, 192, 0, stream>>>(
      H, x, nptr,
      fg_w_h, fg_w_x, ig_w_h, ig_w_x,
      in_w_h, in_w_x, og_w_h, og_w_x,
      Apk, Wpk);
  dim3 grid(NDIM / BN, BATCH / BM);  // (16, 64) = 1024 blocks = 4/CU
  gemm_lstm<<<grid, 256, 0, stream>>>(Apk, Wpk, C,
                                      fg_w_c, fg_b, ig_w_c, ig_b, in_b,
                                      og_w_cn, og_b, (float*)d_out);
}

// Round 5
// 258.008 us; speedup vs baseline: 1.0263x; 1.0139x over previous
//
#include <hip/hip_runtime.h>

// ---------------------------------------------------------------------------
// LSTM (Alex Graves) single step, batch 8192 — fused GEMM+epilogue, r10.
// EXACT r5 revert (best measured: 254.0 / 254.3 us, twice, two sessions).
// Session ledger: r6 (256^2 2-phase dbuf) +4.7; r7 (coarse counted-vmcnt)
// +6.9; r8 (faithful 8-phase) +10.5; r9 (r5 gemm + 16-row pack) +7.3.
// Every deviation from this configuration measured worse. r9 isolated the
// pack variable: r5's 10240-tiny-block pack (40 blocks/CU of pure TLP)
// beats fat-block variants. This round is the controlled re-anchor.
//   A = [H | x[:,n,:]]  (8192 x 768)  fp16-packed
//   W rows permuted:  row c = gate g=(c>>4)&3, unit jj=((c>>6)<<4)|(c&15)
//     -> register j = gate, lane&15 = jj: epilogue entirely in registers.
//   out[0:8192*512) = cm ; out[8192*512:) = h
// ---------------------------------------------------------------------------

typedef _Float16 half8 __attribute__((ext_vector_type(8)));
typedef _Float16 half4v __attribute__((ext_vector_type(4)));
typedef float floatx4 __attribute__((ext_vector_type(4)));

#define BATCH 8192
#define NSTEPS 16
#define IN_F 256
#define OUT_F 512
#define KDIM 768    // OUT_F + IN_F
#define NDIM 2048   // 4 * OUT_F
#define HSIZE ((size_t)BATCH * OUT_F)

#define BM 128
#define BN 128
#define BK 64

__device__ __forceinline__ void async_copy16(const void* gptr, void* lptr) {
  __builtin_amdgcn_global_load_lds(
      (const __attribute__((address_space(1))) unsigned int*)gptr,
      (__attribute__((address_space(3))) unsigned int*)lptr,
      16, 0, 0);
}

__device__ __forceinline__ float sigmoidf_(float x) {
  return 1.0f / (1.0f + __expf(-x));
}

__device__ __forceinline__ float tanhf_(float x) {
  x = fminf(fmaxf(x, -20.0f), 20.0f);   // __expf(|2x|>~176) would inf->NaN
  float e = __expf(2.0f * x);
  return (e - 1.0f) / (e + 1.0f);
}

// ------------------- merged pack: A rows then W rows -----------------------
__global__ void pack_AW(const float* __restrict__ H, const float* __restrict__ x,
                        const int* __restrict__ nptr,
                        const float* __restrict__ fg_w_h, const float* __restrict__ fg_w_x,
                        const float* __restrict__ ig_w_h, const float* __restrict__ ig_w_x,
                        const float* __restrict__ in_w_h, const float* __restrict__ in_w_x,
                        const float* __restrict__ og_w_h, const float* __restrict__ og_w_x,
                        _Float16* __restrict__ A, _Float16* __restrict__ W) {
  const int blk = blockIdx.x;
  const int k = threadIdx.x * 4;
  const float* src;
  _Float16* dst;
  if (blk < BATCH) {
    const int b = blk;
    if (k < OUT_F) {
      src = H + (size_t)b * OUT_F + k;
    } else {
      const int n = *nptr;
      src = x + ((size_t)b * NSTEPS + n) * IN_F + (k - OUT_F);
    }
    dst = A + (size_t)b * KDIM + k;
  } else {
    const int row = blk - BATCH;
    const int g  = (row >> 4) & 3;
    const int jj = ((row >> 6) << 4) | (row & 15);
    if (k < OUT_F) {
      const float* wh = (g == 0) ? fg_w_h : (g == 1) ? ig_w_h : (g == 2) ? in_w_h : og_w_h;
      src = wh + (size_t)jj * OUT_F + k;
    } else {
      const float* wx = (g == 0) ? fg_w_x : (g == 1) ? ig_w_x : (g == 2) ? in_w_x : og_w_x;
      src = wx + (size_t)jj * IN_F + (k - OUT_F);
    }
    dst = W + (size_t)row * KDIM + k;
  }
  float4 v = *(const float4*)src;
  half4v h = {(_Float16)v.x, (_Float16)v.y, (_Float16)v.z, (_Float16)v.w};
  *(half4v*)dst = h;
}

// ---------------------- fused GEMM + gate epilogue -------------------------
// 128x128 tile, BK=64, 256 thr / 4 waves, each wave 64x64 (4x4 MFMA tiles).
// LDS 16B-granule XOR swizzle applied on the GLOBAL address side.
// Block's output region: rows m0..m0+127, units jj in [bx*32, bx*32+32):
// 128 B per row per tile -> full-line coalesced stores after LDS transpose.
__global__ __launch_bounds__(256, 4) void gemm_lstm(
    const _Float16* __restrict__ A, const _Float16* __restrict__ W,
    const float* __restrict__ C,
    const float* __restrict__ fg_w_c, const float* __restrict__ fg_b,
    const float* __restrict__ ig_w_c, const float* __restrict__ ig_b,
    const float* __restrict__ in_b,
    const float* __restrict__ og_w_cn, const float* __restrict__ og_b,
    float* __restrict__ out) {
  __shared__ __align__(16) char smem[32768];
  _Float16* As = (_Float16*)smem;            // 16 KB (K-loop)
  _Float16* Bs = (_Float16*)(smem + 16384);  // 16 KB (K-loop)
  float* cmS = (float*)smem;                 // 16 KB (epilogue, 128x32)
  float* hS  = (float*)(smem + 16384);       // 16 KB (epilogue, 128x32)

  const int tid = threadIdx.x;
  const int lane = tid & 63;
  const int wave = tid >> 6;
  const int quad = lane >> 4;
  const int l16 = lane & 15;
  const int m0 = blockIdx.y * BM;
  const int n0 = blockIdx.x * BN;
  const int mw = (wave >> 1) * 64;
  const int nw = (wave & 1) * 64;

  // this lane's output unit
  const int jj = (((n0 + nw) >> 6) << 4) | l16;
  const float fwc = fg_w_c[jj], fb = fg_b[jj];
  const float iwc = ig_w_c[jj], ib = ig_b[jj];
  const float nb  = in_b[jj];
  const float owc = og_w_cn[jj], ob = og_b[jj];

  floatx4 acc[4][4] = {};

  for (int kt = 0; kt < KDIM; kt += BK) {
    __syncthreads();
#pragma unroll
    for (int r = 0; r < 4; ++r) {
      const int g = r * 256 + tid;       // 16B granule index
      const int row = g >> 3;
      const int cl = g & 7;
      const int cg = cl ^ (row & 7);     // swizzled global chunk
      async_copy16(A + (size_t)(m0 + row) * KDIM + kt + cg * 8,
                   As + g * 8);
      async_copy16(W + (size_t)(n0 + row) * KDIM + kt + cg * 8,
                   Bs + g * 8);
    }
    __syncthreads();

#pragma unroll
    for (int ks = 0; ks < 2; ++ks) {
      half8 af[4], bf[4];
#pragma unroll
      for (int i = 0; i < 4; ++i) {
        const int row = mw + i * 16 + l16;
        const int chunk = ks * 4 + quad;
        const int gran = row * 8 + (chunk ^ (row & 7));
        af[i] = *(const half8*)(As + gran * 8);
      }
#pragma unroll
      for (int j = 0; j < 4; ++j) {
        const int row = nw + j * 16 + l16;
        const int chunk = ks * 4 + quad;
        const int gran = row * 8 + (chunk ^ (row & 7));
        bf[j] = *(const half8*)(Bs + gran * 8);
      }
#pragma unroll
      for (int i = 0; i < 4; ++i)
#pragma unroll
        for (int j = 0; j < 4; ++j)
          acc[i][j] = __builtin_amdgcn_mfma_f32_16x16x32_f16(af[i], bf[j], acc[i][j], 0, 0, 0);
    }
  }

  // ---- epilogue. C/D: col=lane&15 (=jj lane), row=quad*4+r ----
  // batched C loads first (overlap their HBM latency with tanh below)
  float cv[16];
#pragma unroll
  for (int i = 0; i < 4; ++i) {
    const int rbase = m0 + mw + i * 16 + quad * 4;
#pragma unroll
    for (int r = 0; r < 4; ++r)
      cv[i * 4 + r] = C[(size_t)(rbase + r) * OUT_F + jj];
  }
  float inn[16];
#pragma unroll
  for (int i = 0; i < 4; ++i)
#pragma unroll
    for (int r = 0; r < 4; ++r)
      inn[i * 4 + r] = tanhf_(acc[i][2][r] + nb);

  __syncthreads();   // all K-loop ds_reads complete before As/Bs overwrite

  const int jjloc = (nw >> 6) * 16 + l16;      // 0..31 within block tile
#pragma unroll
  for (int i = 0; i < 4; ++i) {
    const int rloc0 = mw + i * 16 + quad * 4;  // block-local row 0..127
#pragma unroll
    for (int r = 0; r < 4; ++r) {
      const float c = cv[i * 4 + r];
      const float fg  = sigmoidf_(fwc * c + acc[i][0][r] + fb);
      const float ig  = sigmoidf_(iwc * c + acc[i][1][r] + ib);
      const float cm  = fg * c + ig * inn[i * 4 + r];
      const float og  = sigmoidf_(owc * cm + acc[i][3][r] + ob);
      cmS[(rloc0 + r) * 32 + jjloc] = cm;
      hS [(rloc0 + r) * 32 + jjloc] = og * tanhf_(cm);
    }
  }
  __syncthreads();

  // cooperative coalesced store: 128 rows x 32 cols per tile; thread q-loop
  // covers 4 float4 each; wave = 8 rows x 128 B contiguous per instruction.
  const int bx32 = blockIdx.x * 32;
#pragma unroll
  for (int q = 0; q < 4; ++q) {
    const int idx = q * 256 + tid;
    const int row = idx >> 3;
    const int c4 = idx & 7;
    const size_t gbase = (size_t)(m0 + row) * OUT_F + bx32 + c4 * 4;
    *(float4*)(out + gbase) = *(const float4*)(cmS + row * 32 + c4 * 4);
    *(float4*)(out + HSIZE + gbase) = *(const float4*)(hS + row * 32 + c4 * 4);
  }
}

// ---------------------------------------------------------------------------
extern "C" void kernel_launch(void* const* d_in, const int* in_sizes, int n_in,
                              void* d_out, int out_size, void* d_ws, size_t ws_size,
                              hipStream_t stream) {
  const float* x       = (const float*)d_in[0];
  const float* C       = (const float*)d_in[1];
  const float* H       = (const float*)d_in[2];
  const float* fg_w_c  = (const float*)d_in[3];
  const float* fg_w_h  = (const float*)d_in[4];
  const float* fg_w_x  = (const float*)d_in[5];
  const float* fg_b    = (const float*)d_in[6];
  const float* ig_w_c  = (const float*)d_in[7];
  const float* ig_w_h  = (const float*)d_in[8];
  const float* ig_w_x  = (const float*)d_in[9];
  const float* ig_b    = (const float*)d_in[10];
  const float* in_w_h  = (const float*)d_in[11];
  const float* in_w_x  = (const float*)d_in[12];
  const float* in_b    = (const float*)d_in[13];
  const float* og_w_cn = (const float*)d_in[14];
  const float* og_w_h  = (const float*)d_in[15];
  const float* og_w_x  = (const float*)d_in[16];
  const float* og_b    = (const float*)d_in[17];
  const int*   nptr    = (const int*)d_in[18];

  char* ws = (char*)d_ws;
  _Float16* Apk = (_Float16*)ws;                // 8192*768*2 = 12,582,912 B
  _Float16* Wpk = (_Float16*)(ws + 12582912);   // 2048*768*2 =  3,145,728 B
  (void)ws_size; (void)in_sizes; (void)n_in; (void)out_size;

  pack_AW<<<BATCH + NDIM, 192, 0, stream>>>(H, x, nptr,
                                            fg_w_h, fg_w_x, ig_w_h, ig_w_x,
                                            in_w_h, in_w_x, og_w_h, og_w_x,
                                            Apk, Wpk);
  dim3 grid(NDIM / BN, BATCH / BM);  // (16, 64) = 1024 blocks = 4/CU
  gemm_lstm<<<grid, 256, 0, stream>>>(Apk, Wpk, C,
                                      fg_w_c, fg_b, ig_w_c, ig_b, in_b,
                                      og_w_cn, og_b, (float*)d_out);
}